// Round 2
// baseline (84.382 us; speedup 1.0000x reference)
//
#include <hip/hip_runtime.h>

#define N 2048
#define B 16
#define STRENGTH 0.1f
#define RADIUS 2310.0f
#define CHUNKS 8          // j-chunks per batch in kernel 1
#define BLK 256

// Kernel 1: per (batch, j-chunk) block. d[b,j] = sum_i |x[b,i]-x[b,j]|.
// The i-loop reads are wave-uniform -> compiler emits s_load (SMEM pipe),
// so the inner loop is pure VALU: v_sub_f32 (sgpr src) + v_add_f32 with
// abs() input modifier = 2 VALU/element, no LDS, no per-element VMEM.
__global__ __launch_bounds__(BLK) void repulsion_dist_kernel(
    const float* __restrict__ x, float* __restrict__ partials) {
  const int b = blockIdx.x >> 3;     // / CHUNKS
  const int chunk = blockIdx.x & 7;  // % CHUNKS
  const int tid = threadIdx.x;
  const float* __restrict__ xb = x + b * N;

  const int j = chunk * BLK + tid;
  const float xj = xb[j];            // per-lane, coalesced

  // 8 independent accumulators, SAME grouping/order as the passing round:
  // element i goes to acc (i&7), ascending i within each acc.
  float a0 = 0.f, a1 = 0.f, a2 = 0.f, a3 = 0.f;
  float a4 = 0.f, a5 = 0.f, a6 = 0.f, a7 = 0.f;
#pragma unroll 4
  for (int i = 0; i < N; i += 8) {
    a0 += fabsf(xb[i + 0] - xj);
    a1 += fabsf(xb[i + 1] - xj);
    a2 += fabsf(xb[i + 2] - xj);
    a3 += fabsf(xb[i + 3] - xj);
    a4 += fabsf(xb[i + 4] - xj);
    a5 += fabsf(xb[i + 5] - xj);
    a6 += fabsf(xb[i + 6] - xj);
    a7 += fabsf(xb[i + 7] - xj);
  }
  const float d = ((a0 + a1) + (a2 + a3)) + ((a4 + a5) + (a6 + a7));

  float w = (d < RADIUS) ? STRENGTH : 0.f;
  float wx = w * xj;

  // wave (64) reduce, then cross-wave via LDS
#pragma unroll
  for (int m = 32; m >= 1; m >>= 1) {
    w += __shfl_xor(w, m, 64);
    wx += __shfl_xor(wx, m, 64);
  }
  __shared__ float sw_s[4], swx_s[4];
  const int wave = tid >> 6, lane = tid & 63;
  if (lane == 0) { sw_s[wave] = w; swx_s[wave] = wx; }
  __syncthreads();
  if (tid == 0) {
    partials[blockIdx.x * 2 + 0] = (sw_s[0] + sw_s[1]) + (sw_s[2] + sw_s[3]);
    partials[blockIdx.x * 2 + 1] = (swx_s[0] + swx_s[1]) + (swx_s[2] + swx_s[3]);
  }
}

// Kernel 2: single block. 16 lanes per batch: combine partials, compute
// ||Sxw - Sw*x[b,:]||_2 with float4 loads, then mean over batches.
__global__ __launch_bounds__(BLK) void repulsion_norm_kernel(
    const float* __restrict__ x, const float* __restrict__ partials,
    float* __restrict__ out) {
  const int tid = threadIdx.x;  // 0..255
  const int b = tid >> 4;       // batch 0..15 (4 batches per wave)
  const int u = tid & 15;       // lane-in-group

  float sw = 0.f, swx = 0.f;
  if (u < CHUNKS) {
    sw  = partials[(b * CHUNKS + u) * 2 + 0];
    swx = partials[(b * CHUNKS + u) * 2 + 1];
  }
#pragma unroll
  for (int m = 8; m >= 1; m >>= 1) {
    sw += __shfl_xor(sw, m, 16);
    swx += __shfl_xor(swx, m, 16);
  }

  const float4* __restrict__ xb4 = (const float4*)(x + b * N);
  float c0 = 0.f, c1 = 0.f, c2 = 0.f, c3 = 0.f;
#pragma unroll 4
  for (int m = 0; m < N / 64; ++m) {  // 32 iterations of 16B loads
    const float4 v = xb4[m * 16 + u];
    float r0 = swx - sw * v.x; c0 = fmaf(r0, r0, c0);
    float r1 = swx - sw * v.y; c1 = fmaf(r1, r1, c1);
    float r2 = swx - sw * v.z; c2 = fmaf(r2, r2, c2);
    float r3 = swx - sw * v.w; c3 = fmaf(r3, r3, c3);
  }
  float acc = (c0 + c1) + (c2 + c3);
#pragma unroll
  for (int m = 8; m >= 1; m >>= 1) acc += __shfl_xor(acc, m, 16);

  __shared__ float norms[B];
  if (u == 0) norms[b] = sqrtf(acc);
  __syncthreads();
  if (tid == 0) {
    float s = 0.f;
#pragma unroll
    for (int i = 0; i < B; ++i) s += norms[i];
    out[0] = s * (1.0f / (float)B);
  }
}

extern "C" void kernel_launch(void* const* d_in, const int* in_sizes, int n_in,
                              void* d_out, int out_size, void* d_ws, size_t ws_size,
                              hipStream_t stream) {
  const float* x = (const float*)d_in[0];
  float* partials = (float*)d_ws;  // B*CHUNKS*2 floats = 1 KiB
  repulsion_dist_kernel<<<B * CHUNKS, BLK, 0, stream>>>(x, partials);
  repulsion_norm_kernel<<<1, BLK, 0, stream>>>(x, partials, (float*)d_out);
}

// Round 3
// 71.678 us; speedup vs baseline: 1.1772x; 1.1772x over previous
//
#include <hip/hip_runtime.h>

#define N 2048
#define B 16
#define STRENGTH 0.1f
#define RADIUS 2310.0f
#define JCHUNKS 16        // j-chunks per batch in kernel 1 (256 blocks total)
#define BLK1 128          // 2 waves/block -> 1 block per CU over 256 CUs
#define BLK2 256

// Kernel 1: per (batch, j-chunk) block. d[b,j] = sum_i |x[b,i]-x[b,j]|.
// i-stream comes from LDS via float4 broadcast reads (ds_read_b128, all
// lanes same address = conflict-free, ~3 cyc/element issue) — R1 showed the
// LDS pipe beats VMEM/SMEM here; R2 showed uniform global reads regress.
__global__ __launch_bounds__(BLK1) void repulsion_dist_kernel(
    const float* __restrict__ x, float* __restrict__ partials) {
  __shared__ float4 xs4[N / 4];
  const int b = blockIdx.x >> 4;      // / JCHUNKS
  const int chunk = blockIdx.x & 15;  // % JCHUNKS
  const int tid = threadIdx.x;
  const float* __restrict__ xb = x + b * N;
  const float4* __restrict__ xb4 = (const float4*)xb;

#pragma unroll
  for (int k = 0; k < N / 4 / BLK1; ++k) xs4[tid + BLK1 * k] = xb4[tid + BLK1 * k];
  __syncthreads();

  const int j = chunk * BLK1 + tid;
  const float xj = ((const float*)xs4)[j];

  // 8 independent accumulators; SAME grouping/order as passing rounds:
  // element i -> acc (i&7), ascending i within each acc.
  float a0 = 0.f, a1 = 0.f, a2 = 0.f, a3 = 0.f;
  float a4 = 0.f, a5 = 0.f, a6 = 0.f, a7 = 0.f;
#pragma unroll 4
  for (int i4 = 0; i4 < N / 4; i4 += 2) {
    const float4 v0 = xs4[i4 + 0];
    const float4 v1 = xs4[i4 + 1];
    a0 += fabsf(v0.x - xj);
    a1 += fabsf(v0.y - xj);
    a2 += fabsf(v0.z - xj);
    a3 += fabsf(v0.w - xj);
    a4 += fabsf(v1.x - xj);
    a5 += fabsf(v1.y - xj);
    a6 += fabsf(v1.z - xj);
    a7 += fabsf(v1.w - xj);
  }
  const float d = ((a0 + a1) + (a2 + a3)) + ((a4 + a5) + (a6 + a7));

  float w = (d < RADIUS) ? STRENGTH : 0.f;
  float wx = w * xj;

  // wave (64) reduce, then cross-wave via LDS
#pragma unroll
  for (int m = 32; m >= 1; m >>= 1) {
    w += __shfl_xor(w, m, 64);
    wx += __shfl_xor(wx, m, 64);
  }
  __shared__ float sw_s[2], swx_s[2];
  const int wave = tid >> 6, lane = tid & 63;
  if (lane == 0) { sw_s[wave] = w; swx_s[wave] = wx; }
  __syncthreads();
  if (tid == 0) {
    partials[blockIdx.x * 2 + 0] = sw_s[0] + sw_s[1];
    partials[blockIdx.x * 2 + 1] = swx_s[0] + swx_s[1];
  }
}

// Kernel 2: single block. 16 lanes per batch: combine the 16 chunk partials,
// compute ||Sxw - Sw*x[b,:]||_2 with float4 loads, then mean over batches.
__global__ __launch_bounds__(BLK2) void repulsion_norm_kernel(
    const float* __restrict__ x, const float* __restrict__ partials,
    float* __restrict__ out) {
  const int tid = threadIdx.x;  // 0..255
  const int b = tid >> 4;       // batch 0..15 (4 batches per wave)
  const int u = tid & 15;       // lane-in-group: chunk index 0..15

  float sw  = partials[(b * JCHUNKS + u) * 2 + 0];
  float swx = partials[(b * JCHUNKS + u) * 2 + 1];
#pragma unroll
  for (int m = 8; m >= 1; m >>= 1) {
    sw += __shfl_xor(sw, m, 16);
    swx += __shfl_xor(swx, m, 16);
  }

  const float4* __restrict__ xb4 = (const float4*)(x + b * N);
  float c0 = 0.f, c1 = 0.f, c2 = 0.f, c3 = 0.f;
#pragma unroll 4
  for (int m = 0; m < N / 64; ++m) {  // 32 iterations of 16B loads
    const float4 v = xb4[m * 16 + u];
    float r0 = swx - sw * v.x; c0 = fmaf(r0, r0, c0);
    float r1 = swx - sw * v.y; c1 = fmaf(r1, r1, c1);
    float r2 = swx - sw * v.z; c2 = fmaf(r2, r2, c2);
    float r3 = swx - sw * v.w; c3 = fmaf(r3, r3, c3);
  }
  float acc = (c0 + c1) + (c2 + c3);
#pragma unroll
  for (int m = 8; m >= 1; m >>= 1) acc += __shfl_xor(acc, m, 16);

  __shared__ float norms[B];
  if (u == 0) norms[b] = sqrtf(acc);
  __syncthreads();
  if (tid == 0) {
    float s = 0.f;
#pragma unroll
    for (int i = 0; i < B; ++i) s += norms[i];
    out[0] = s * (1.0f / (float)B);
  }
}

extern "C" void kernel_launch(void* const* d_in, const int* in_sizes, int n_in,
                              void* d_out, int out_size, void* d_ws, size_t ws_size,
                              hipStream_t stream) {
  const float* x = (const float*)d_in[0];
  float* partials = (float*)d_ws;  // B*JCHUNKS*2 floats = 2 KiB
  repulsion_dist_kernel<<<B * JCHUNKS, BLK1, 0, stream>>>(x, partials);
  repulsion_norm_kernel<<<1, BLK2, 0, stream>>>(x, partials, (float*)d_out);
}

// Round 4
// 70.412 us; speedup vs baseline: 1.1984x; 1.0180x over previous
//
#include <hip/hip_runtime.h>

#define N 2048
#define B 16
#define STRENGTH 0.1f
#define RADIUS 2310.0f
#define JCHUNKS 16        // j-chunks per batch in kernel 1 (256 blocks total)
#define BLK1 128          // 2 waves/block -> 1 block per CU over 256 CUs
#define BLK2 256

// Kernel 1: per (batch, j-chunk) block. d[b,j] = sum_i |x[b,i]-x[b,j]|.
// i-stream via LDS float4 broadcast reads (conflict-free). Summation order
// (i -> acc i&7, ascending) is bit-identical to the passing rounds.
// Block 0 thread 0 also zeroes d_out so kernel 2 can atomicAdd into it.
__global__ __launch_bounds__(BLK1) void repulsion_dist_kernel(
    const float* __restrict__ x, float* __restrict__ partials,
    float* __restrict__ out) {
  __shared__ float4 xs4[N / 4];
  const int b = blockIdx.x >> 4;      // / JCHUNKS
  const int chunk = blockIdx.x & 15;  // % JCHUNKS
  const int tid = threadIdx.x;
  if (blockIdx.x == 0 && tid == 0) out[0] = 0.f;  // k2 runs strictly after k1
  const float4* __restrict__ xb4 = (const float4*)(x + b * N);

#pragma unroll
  for (int k = 0; k < N / 4 / BLK1; ++k) xs4[tid + BLK1 * k] = xb4[tid + BLK1 * k];
  __syncthreads();

  const int j = chunk * BLK1 + tid;
  const float xj = ((const float*)xs4)[j];

  float a0 = 0.f, a1 = 0.f, a2 = 0.f, a3 = 0.f;
  float a4 = 0.f, a5 = 0.f, a6 = 0.f, a7 = 0.f;
#pragma unroll 4
  for (int i4 = 0; i4 < N / 4; i4 += 2) {
    const float4 v0 = xs4[i4 + 0];
    const float4 v1 = xs4[i4 + 1];
    a0 += fabsf(v0.x - xj);
    a1 += fabsf(v0.y - xj);
    a2 += fabsf(v0.z - xj);
    a3 += fabsf(v0.w - xj);
    a4 += fabsf(v1.x - xj);
    a5 += fabsf(v1.y - xj);
    a6 += fabsf(v1.z - xj);
    a7 += fabsf(v1.w - xj);
  }
  const float d = ((a0 + a1) + (a2 + a3)) + ((a4 + a5) + (a6 + a7));

  float w = (d < RADIUS) ? STRENGTH : 0.f;
  float wx = w * xj;

#pragma unroll
  for (int m = 32; m >= 1; m >>= 1) {
    w += __shfl_xor(w, m, 64);
    wx += __shfl_xor(wx, m, 64);
  }
  __shared__ float sw_s[2], swx_s[2];
  const int wave = tid >> 6, lane = tid & 63;
  if (lane == 0) { sw_s[wave] = w; swx_s[wave] = wx; }
  __syncthreads();
  if (tid == 0) {
    partials[blockIdx.x * 2 + 0] = sw_s[0] + sw_s[1];
    partials[blockIdx.x * 2 + 1] = swx_s[0] + swx_s[1];
  }
}

// Kernel 2: one block per batch (16 blocks). Combine the 16 chunk partials,
// compute ||Sxw - Sw*x[b,:]||_2, atomicAdd(norm/B) into out.
__global__ __launch_bounds__(BLK2) void repulsion_norm_kernel(
    const float* __restrict__ x, const float* __restrict__ partials,
    float* __restrict__ out) {
  const int b = blockIdx.x;
  const int tid = threadIdx.x;  // 0..255

  // Sum the 16 (sw, swx) chunk partials on wave 0, broadcast via LDS.
  __shared__ float sw_bc, swx_bc;
  if (tid < 64) {
    float sw = 0.f, swx = 0.f;
    if (tid < JCHUNKS) {
      sw  = partials[(b * JCHUNKS + tid) * 2 + 0];
      swx = partials[(b * JCHUNKS + tid) * 2 + 1];
    }
#pragma unroll
    for (int m = 8; m >= 1; m >>= 1) {
      sw += __shfl_xor(sw, m, 16);
      swx += __shfl_xor(swx, m, 16);
    }
    if (tid == 0) { sw_bc = sw; swx_bc = swx; }
  }
  __syncthreads();
  const float sw = sw_bc, swx = swx_bc;

  const float4* __restrict__ xb4 = (const float4*)(x + b * N);
  float acc = 0.f;
#pragma unroll
  for (int t = 0; t < N / 4 / BLK2; ++t) {  // 2 float4 per thread
    const float4 v = xb4[t * BLK2 + tid];
    float r0 = swx - sw * v.x; acc = fmaf(r0, r0, acc);
    float r1 = swx - sw * v.y; acc = fmaf(r1, r1, acc);
    float r2 = swx - sw * v.z; acc = fmaf(r2, r2, acc);
    float r3 = swx - sw * v.w; acc = fmaf(r3, r3, acc);
  }
#pragma unroll
  for (int m = 32; m >= 1; m >>= 1) acc += __shfl_xor(acc, m, 64);

  __shared__ float wsum[BLK2 / 64];
  const int wave = tid >> 6, lane = tid & 63;
  if (lane == 0) wsum[wave] = acc;
  __syncthreads();
  if (tid == 0) {
    const float tot = (wsum[0] + wsum[1]) + (wsum[2] + wsum[3]);
    atomicAdd(out, sqrtf(tot) * (1.0f / (float)B));
  }
}

extern "C" void kernel_launch(void* const* d_in, const int* in_sizes, int n_in,
                              void* d_out, int out_size, void* d_ws, size_t ws_size,
                              hipStream_t stream) {
  const float* x = (const float*)d_in[0];
  float* partials = (float*)d_ws;  // B*JCHUNKS*2 floats = 2 KiB
  float* out = (float*)d_out;
  repulsion_dist_kernel<<<B * JCHUNKS, BLK1, 0, stream>>>(x, partials, out);
  repulsion_norm_kernel<<<B, BLK2, 0, stream>>>(x, partials, out);
}